// Round 1
// baseline (196.197 us; speedup 1.0000x reference)
//
#include <hip/hip_runtime.h>

#define Bn 16
#define Cn 64
#define Hn 128
#define Wn 128
#define HWn (Hn * Wn)

// ---------------------------------------------------------------------------
// Kernel 1: generate per-(batch,channel) 3x3 kernels.
//   hid[b,i] = lrelu(sum_j d[b,j] * Wk1[i,j])          (16,64)
//   kern[b,o] = sum_j hid[b,j] * Wk2[o,j]  o in [0,576) (16,576)
// Layout in ws: kern[b*576 + c*9 + tap]
// ---------------------------------------------------------------------------
__global__ void gen_kern(const float* __restrict__ d,
                         const float* __restrict__ Wk1,
                         const float* __restrict__ Wk2,
                         float* __restrict__ kern_out) {
    const int b = blockIdx.x;   // 16 blocks
    const int t = threadIdx.x;  // 64 threads
    __shared__ float hid[64];

    float s = 0.f;
    #pragma unroll
    for (int j = 0; j < 64; ++j) s += d[b * 64 + j] * Wk1[t * 64 + j];
    hid[t] = (s >= 0.f) ? s : 0.1f * s;
    __syncthreads();

    // 576 outputs / 64 threads = 9 per thread
    for (int r = 0; r < 9; ++r) {
        const int o = r * 64 + t;
        float k = 0.f;
        #pragma unroll
        for (int j = 0; j < 64; ++j) k += hid[j] * Wk2[o * 64 + j];
        kern_out[b * 576 + o] = k;
    }
}

// ---------------------------------------------------------------------------
// Kernel 2: fused dynamic depthwise 3x3 (SAME) -> lrelu -> 1x1 conv + bias.
// One thread per output pixel (b,h,w); 64 fp32 accumulators (one per output
// channel) in VGPRs. kern taps and Wc are wave-uniform -> scalar (SMEM) loads.
// Block = 256 threads = 64 (w) x 4 (h). Grid = (W/64, H/4, B) = 1024 blocks.
// ---------------------------------------------------------------------------
__global__ __launch_bounds__(256, 4)
void da_main(const float* __restrict__ x,
             const float* __restrict__ kern,
             const float* __restrict__ Wc,
             const float* __restrict__ bc,
             float* __restrict__ out) {
    const int w = (blockIdx.x << 6) + (threadIdx.x & 63);
    const int h = (blockIdx.y << 2) + (threadIdx.x >> 6);
    const int b = blockIdx.z;

    const float* __restrict__ xb = x + (size_t)b * Cn * HWn;
    const float* __restrict__ kb = kern + b * 576;

    // Clamped tap offsets + validity masks (per-thread, computed once)
    int rofs[3];  bool rok[3];
    int cofs[3];  bool cok[3];
    #pragma unroll
    for (int i = 0; i < 3; ++i) {
        int hh = h + i - 1;
        rok[i] = (hh >= 0) && (hh < Hn);
        rofs[i] = (hh < 0 ? 0 : (hh >= Hn ? Hn - 1 : hh)) * Wn;
        int ww = w + i - 1;
        cok[i] = (ww >= 0) && (ww < Wn);
        cofs[i] = (ww < 0 ? 0 : (ww >= Wn ? Wn - 1 : ww));
    }
    int  off[9];
    bool msk[9];
    #pragma unroll
    for (int r = 0; r < 3; ++r)
        #pragma unroll
        for (int c2 = 0; c2 < 3; ++c2) {
            off[r * 3 + c2] = rofs[r] + cofs[c2];
            msk[r * 3 + c2] = rok[r] && cok[c2];
        }

    float acc[64];
    #pragma unroll
    for (int o = 0; o < 64; ++o) acc[o] = bc[o];

    for (int c = 0; c < Cn; ++c) {
        const float* __restrict__ xc = xb + c * HWn;
        // 9 kern taps: wave-uniform -> SGPRs
        float v = 0.f;
        #pragma unroll
        for (int i = 0; i < 9; ++i) {
            float t = msk[i] ? xc[off[i]] : 0.f;
            v += t * kb[c * 9 + i];
        }
        v = (v >= 0.f) ? v : 0.1f * v;
        // 1x1 conv: Wc[o*64+c] wave-uniform -> SGPR operand of v_fmac
        #pragma unroll
        for (int o = 0; o < 64; ++o)
            acc[o] += v * Wc[o * 64 + c];
    }

    float* __restrict__ ob = out + (size_t)b * Cn * HWn + h * Wn + w;
    #pragma unroll
    for (int o = 0; o < 64; ++o)
        ob[(size_t)o * HWn] = acc[o];
}

// ---------------------------------------------------------------------------
extern "C" void kernel_launch(void* const* d_in, const int* in_sizes, int n_in,
                              void* d_out, int out_size, void* d_ws, size_t ws_size,
                              hipStream_t stream) {
    const float* x   = (const float*)d_in[0];
    const float* d   = (const float*)d_in[1];
    const float* Wk1 = (const float*)d_in[2];
    const float* Wk2 = (const float*)d_in[3];
    const float* Wc  = (const float*)d_in[4];
    const float* bc  = (const float*)d_in[5];
    float* out  = (float*)d_out;
    float* kern = (float*)d_ws;   // 16*576 floats = 36 KB

    gen_kern<<<dim3(Bn), dim3(64), 0, stream>>>(d, Wk1, Wk2, kern);
    da_main<<<dim3(Wn / 64, Hn / 4, Bn), dim3(256), 0, stream>>>(x, kern, Wc, bc, out);
}